// Round 2
// baseline (432.251 us; speedup 1.0000x reference)
//
#include <hip/hip_runtime.h>

// 8-point DCT-II matrix M[u][i] = c(u) * cos((2i+1) u pi / 16),
// c(0)=sqrt(1/8), c(u>0)=0.5.  K[u*8+v, i*8+j] = M[u][i]*M[v][j].
#define E8 0.35355339059327373f
#define C1 0.49039264020161522f
#define C3 0.41573480615127262f
#define C5 0.27778511650980114f
#define C7 0.09754516100806412f
#define D1 0.46193976625564337f
#define D3 0.19134171618254492f

static __device__ const float MK[8][8] = {
    { E8,  E8,  E8,  E8,  E8,  E8,  E8,  E8},
    { C1,  C3,  C5,  C7, -C7, -C5, -C3, -C1},
    { D1,  D3, -D3, -D1, -D1, -D3,  D3,  D1},
    { C3, -C7, -C1, -C5,  C5,  C1,  C7, -C3},
    { E8, -E8, -E8,  E8,  E8, -E8, -E8,  E8},
    { C5, -C1,  C7,  C3, -C3, -C7,  C1, -C5},
    { D3, -D1,  D1, -D3, -D3,  D1, -D1,  D3},
    { C7, -C5,  C3, -C1,  C1, -C3,  C5, -C7},
};

__global__ __launch_bounds__(256) void dct_sep_kernel(
    const float* __restrict__ x,         // [16, 64, 256, 256]
    const float* __restrict__ backbone,  // [16, 64]
    const float* __restrict__ itw,       // [64]
    float* __restrict__ out)             // [16, 64, 256, 256]
{
    const int HW = 256 * 256;
    const int b = blockIdx.x;            // 4096 blocks
    const int n = b >> 8;                // 256 blocks per sample
    const int pix = ((b & 255) << 8) | threadIdx.x;

    __shared__ float s_sc[64];
    if (threadIdx.x < 64) {
        s_sc[threadIdx.x] = backbone[(n << 6) + threadIdx.x] * itw[threadIdx.x];
    }
    __syncthreads();

    const float* xp = x + (size_t)n * 64 * HW + pix;

    // Load all 64 channels for this pixel (each load coalesced across the wave).
    float xr[8][8];
#pragma unroll
    for (int i = 0; i < 8; ++i) {
#pragma unroll
        for (int j = 0; j < 8; ++j) {
            xr[i][j] = xp[(size_t)(i * 8 + j) * HW];
        }
    }

    // Stage 1: t[i][v] = sum_j M[v][j] * x[i][j]
    float t[8][8];
#pragma unroll
    for (int i = 0; i < 8; ++i) {
#pragma unroll
        for (int v = 0; v < 8; ++v) {
            float a = MK[v][0] * xr[i][0];
#pragma unroll
            for (int j = 1; j < 8; ++j) {
                a = fmaf(MK[v][j], xr[i][j], a);
            }
            t[i][v] = a;
        }
    }

    // Stage 2: y[u][v] = sum_i M[u][i] * t[i][v]; scale and store per u-row
    float* op = out + (size_t)n * 64 * HW + pix;
#pragma unroll
    for (int u = 0; u < 8; ++u) {
#pragma unroll
        for (int v = 0; v < 8; ++v) {
            float a = MK[u][0] * t[0][v];
#pragma unroll
            for (int i = 1; i < 8; ++i) {
                a = fmaf(MK[u][i], t[i][v], a);
            }
            op[(size_t)(u * 8 + v) * HW] = a * s_sc[u * 8 + v];
        }
    }
}

extern "C" void kernel_launch(void* const* d_in, const int* in_sizes, int n_in,
                              void* d_out, int out_size, void* d_ws, size_t ws_size,
                              hipStream_t stream) {
    const float* x        = (const float*)d_in[0];
    const float* backbone = (const float*)d_in[1];
    const float* itw      = (const float*)d_in[2];
    float* out = (float*)d_out;

    // 16 samples * 256*256 pixels / 256 threads = 4096 blocks
    dct_sep_kernel<<<4096, 256, 0, stream>>>(x, backbone, itw, out);
}

// Round 6
// 415.896 us; speedup vs baseline: 1.0393x; 1.0393x over previous
//
#include <hip/hip_runtime.h>

// 8-point DCT-II matrix M[u][i] = c(u) * cos((2i+1) u pi / 16),
// c(0)=sqrt(1/8), c(u>0)=0.5.  K[u*8+v, i*8+j] = M[u][i]*M[v][j].
#define E8 0.35355339059327373f
#define C1 0.49039264020161522f
#define C3 0.41573480615127262f
#define C5 0.27778511650980114f
#define C7 0.09754516100806412f
#define D1 0.46193976625564337f
#define D3 0.19134171618254492f

static __device__ const float MK[8][8] = {
    { E8,  E8,  E8,  E8,  E8,  E8,  E8,  E8},
    { C1,  C3,  C5,  C7, -C7, -C5, -C3, -C1},
    { D1,  D3, -D3, -D1, -D1, -D3,  D3,  D1},
    { C3, -C7, -C1, -C5,  C5,  C1,  C7, -C3},
    { E8, -E8, -E8,  E8,  E8, -E8, -E8,  E8},
    { C5, -C1,  C7,  C3, -C3, -C7,  C1, -C5},
    { D3, -D1,  D1, -D3, -D3,  D1, -D1,  D3},
    { C7, -C5,  C3, -C1,  C1, -C3,  C5, -C7},
};

typedef float f2 __attribute__((ext_vector_type(2)));

__global__ __launch_bounds__(256) void dct_sep_kernel(
    const float* __restrict__ x,         // [16, 64, 256, 256]
    const float* __restrict__ backbone,  // [16, 64]
    const float* __restrict__ itw,       // [64]
    float* __restrict__ out)             // [16, 64, 256, 256]
{
    const int PP = 32768;                // float2 pairs per channel plane (65536/2)
    const int b  = blockIdx.x;           // 2048 blocks
    const int n  = b >> 7;               // 128 blocks per sample
    const int pp = ((b & 127) << 8) | threadIdx.x;   // pixel-pair index

    __shared__ float s_sc[64];
    if (threadIdx.x < 64) {
        s_sc[threadIdx.x] = backbone[(n << 6) + threadIdx.x] * itw[threadIdx.x];
    }
    __syncthreads();

    const f2* xp = (const f2*)x + (size_t)n * 64 * PP + pp;

    // Load all 64 channels for this pixel pair: 8 B/lane, 512 B/wave/instr.
    f2 xr[8][8];
#pragma unroll
    for (int i = 0; i < 8; ++i) {
#pragma unroll
        for (int j = 0; j < 8; ++j) {
            xr[i][j] = __builtin_nontemporal_load(&xp[(size_t)(i * 8 + j) * PP]);
        }
    }

    // Stage 1: t[i][v] = sum_j M[v][j] * x[i][j]  (both pixels)
    f2 t[8][8];
#pragma unroll
    for (int i = 0; i < 8; ++i) {
#pragma unroll
        for (int v = 0; v < 8; ++v) {
            float ax = MK[v][0] * xr[i][0].x;
            float ay = MK[v][0] * xr[i][0].y;
#pragma unroll
            for (int j = 1; j < 8; ++j) {
                ax = fmaf(MK[v][j], xr[i][j].x, ax);
                ay = fmaf(MK[v][j], xr[i][j].y, ay);
            }
            t[i][v].x = ax;
            t[i][v].y = ay;
        }
    }

    // Stage 2: y[u][v] = sum_i M[u][i] * t[i][v]; scale and store (8 B/lane)
    f2* op = (f2*)out + (size_t)n * 64 * PP + pp;
#pragma unroll
    for (int u = 0; u < 8; ++u) {
#pragma unroll
        for (int v = 0; v < 8; ++v) {
            float ax = MK[u][0] * t[0][v].x;
            float ay = MK[u][0] * t[0][v].y;
#pragma unroll
            for (int i = 1; i < 8; ++i) {
                ax = fmaf(MK[u][i], t[i][v].x, ax);
                ay = fmaf(MK[u][i], t[i][v].y, ay);
            }
            const float s = s_sc[u * 8 + v];
            f2 r;
            r.x = ax * s;
            r.y = ay * s;
            __builtin_nontemporal_store(r, &op[(size_t)(u * 8 + v) * PP]);
        }
    }
}

extern "C" void kernel_launch(void* const* d_in, const int* in_sizes, int n_in,
                              void* d_out, int out_size, void* d_ws, size_t ws_size,
                              hipStream_t stream) {
    const float* x        = (const float*)d_in[0];
    const float* backbone = (const float*)d_in[1];
    const float* itw      = (const float*)d_in[2];
    float* out = (float*)d_out;

    // 16 samples * 32768 pixel-pairs / 256 threads = 2048 blocks
    dct_sep_kernel<<<2048, 256, 0, stream>>>(x, backbone, itw, out);
}